// Round 2
// baseline (74.863 us; speedup 1.0000x reference)
//
#include <hip/hip_runtime.h>
#include <hip/hip_bf16.h>

// B=64, N=64, P=128, K=16, M=N*N=4096
// Outputs: Z [B,N] (4096 f32) then w [B,P,M] (33554432 f32), concatenated.

// ---------------------------------------------------------------------------
// Kernel A: wg[k][m] = sum_t weights[k][t]^2 * g[t][m]   (k<16, m<4096, t<4096)
//           E[k][m]  = exp(-wg[k][m])
// grid 256 blocks (16 m-columns each), 256 threads (tt=tid>>4 over t, mm=tid&15 over m)
// ---------------------------------------------------------------------------
__global__ __launch_bounds__(256) void k_wg(const float* __restrict__ W,
                                            const float* __restrict__ G,
                                            float* __restrict__ wg,
                                            float* __restrict__ E) {
    __shared__ float lds[256 * 16];   // 16 KB: staging w^2 chunk, then reduction
    const int tid = threadIdx.x;
    const int tt  = tid >> 4;         // 0..15  (t sub-lane)
    const int mm  = tid & 15;         // 0..15  (m column within tile)
    const int m0  = blockIdx.x * 16;

    float acc[16];
#pragma unroll
    for (int k = 0; k < 16; ++k) acc[k] = 0.f;

    for (int c = 0; c < 16; ++c) {
        const int t0 = c * 256;
        // stage squared weights chunk: lds[tl*16+k] = W[k][t0+tl]^2 (coalesced per k)
#pragma unroll
        for (int k = 0; k < 16; ++k) {
            float v = W[k * 4096 + t0 + tid];
            lds[tid * 16 + k] = v * v;
        }
        __syncthreads();
#pragma unroll 4
        for (int s = 0; s < 16; ++s) {
            const int tl = s * 16 + tt;
            float gv = G[(size_t)(t0 + tl) * 4096 + m0 + mm];
#pragma unroll
            for (int k = 0; k < 16; ++k)
                acc[k] = fmaf(lds[tl * 16 + k], gv, acc[k]);
        }
        __syncthreads();
    }
    // cross-thread reduction over tt groups
#pragma unroll
    for (int k = 0; k < 16; ++k) lds[tid * 16 + k] = acc[k];
    __syncthreads();
    {
        const int k = tid >> 4;
        const int m = tid & 15;
        float s = 0.f;
#pragma unroll
        for (int t = 0; t < 16; ++t)
            s += lds[(t * 16 + m) * 16 + k];
        wg[k * 4096 + m0 + m] = s;
        E[k * 4096 + m0 + m]  = expf(-s);
    }
}

// ---------------------------------------------------------------------------
// Kernel W: w_out[b][p][:] = wg[idx[b,p]][:]   (idx recovered from one-hot mask)
// one block per (b,p); 256 threads write 4096 floats as float4 (1 KB / wave)
// ---------------------------------------------------------------------------
__global__ __launch_bounds__(256) void k_w_out(const float* __restrict__ xmask,
                                               const float* __restrict__ wg,
                                               float* __restrict__ wout) {
    const int bp  = blockIdx.x;       // 0..8191
    const int tid = threadIdx.x;
    const float* xm = xmask + (size_t)bp * 16;
    int k = 0;
#pragma unroll
    for (int i = 0; i < 16; ++i) k = (xm[i] > 0.5f) ? i : k;   // broadcast loads
    const float4* src = (const float4*)(wg + (size_t)k * 4096);
    float4*       dst = (float4*)(wout + (size_t)bp * 4096);
#pragma unroll
    for (int c = 0; c < 4; ++c)
        dst[c * 256 + tid] = src[c * 256 + tid];
}

// ---------------------------------------------------------------------------
// Kernel Z: one block per b.
//   s[k][j] = sum_{p: idx[b,p]==k} x[b] viewed as [128][64]
//   Z[b][i] = sum_k sum_j E[k][i*64+j] * s[k][j]
// ---------------------------------------------------------------------------
__global__ __launch_bounds__(256) void k_z(const float* __restrict__ x,
                                           const float* __restrict__ xmask,
                                           const float* __restrict__ E,
                                           float* __restrict__ zout) {
    __shared__ float xs[8192];        // 32 KB: x[b] flat
    __shared__ float sw[4][16][64];   // 16 KB: per-wave private s accumulators
    __shared__ int   idx[128];
    __shared__ float zr[4][64];
    const int b   = blockIdx.x;
    const int tid = threadIdx.x;
    const int wv  = tid >> 6;         // wave 0..3
    const int ln  = tid & 63;         // lane 0..63

    // load x[b] (8192 floats) coalesced
    const float4* xsrc = (const float4*)(x + (size_t)b * 8192);
#pragma unroll
    for (int c = 0; c < 8; ++c)
        ((float4*)xs)[c * 256 + tid] = xsrc[c * 256 + tid];

    // idx[p] from one-hot mask
    if (tid < 128) {
        const float* xm = xmask + ((size_t)b * 128 + tid) * 16;
        int k = 0;
#pragma unroll
        for (int i = 0; i < 16; ++i) k = (xm[i] > 0.5f) ? i : k;
        idx[tid] = k;
    }
    // zero per-wave accumulators: sw is 4*16*64 = 4096 floats (16 rounds of 256)
#pragma unroll
    for (int c = 0; c < 16; ++c)
        ((float*)sw)[c * 256 + tid] = 0.f;
    __syncthreads();

    // accumulate: wave wv owns p in [wv*32, wv*32+32); lane = j. No races.
    for (int p = wv * 32; p < wv * 32 + 32; ++p) {
        int k = idx[p];
        sw[wv][k][ln] += xs[p * 64 + ln];
    }
    __syncthreads();

    // reduce 4 wave-copies into sw[0]
    for (int e = tid; e < 1024; e += 256) {
        int k2 = e >> 6, j = e & 63;
        sw[0][k2][j] = sw[0][k2][j] + sw[1][k2][j] + sw[2][k2][j] + sw[3][k2][j];
    }
    __syncthreads();

    // Z: thread (kg=tid>>6, i=tid&63) does 4 k's x 64 j MACs
    {
        const int i  = tid & 63;
        const int kg = tid >> 6;
        float a = 0.f;
#pragma unroll
        for (int kk = 0; kk < 4; ++kk) {
            const int k = kg * 4 + kk;
            const float4* Er = (const float4*)(E + k * 4096 + i * 64);
            const float4* sr = (const float4*)(&sw[0][k][0]);
#pragma unroll
            for (int j4 = 0; j4 < 16; ++j4) {
                float4 e4 = Er[j4];
                float4 s4 = sr[j4];
                a = fmaf(e4.x, s4.x, a);
                a = fmaf(e4.y, s4.y, a);
                a = fmaf(e4.z, s4.z, a);
                a = fmaf(e4.w, s4.w, a);
            }
        }
        zr[kg][i] = a;
    }
    __syncthreads();
    if (tid < 64)
        zout[b * 64 + tid] = zr[0][tid] + zr[1][tid] + zr[2][tid] + zr[3][tid];
}

extern "C" void kernel_launch(void* const* d_in, const int* in_sizes, int n_in,
                              void* d_out, int out_size, void* d_ws, size_t ws_size,
                              hipStream_t stream) {
    const float* x     = (const float*)d_in[0];   // [64,64,128]
    const float* xmask = (const float*)d_in[1];   // [64,128,16]
    const float* W     = (const float*)d_in[2];   // [16,4096]
    const float* G     = (const float*)d_in[3];   // [4096,4096]

    float* zout = (float*)d_out;                  // [64,64]
    float* wout = (float*)d_out + 4096;           // [64,128,4096]

    float* wg = (float*)d_ws;                     // 16*4096 f32
    float* E  = wg + 16 * 4096;                   // 16*4096 f32  (512 KB total ws)

    k_wg   <<<256,  256, 0, stream>>>(W, G, wg, E);
    k_w_out<<<8192, 256, 0, stream>>>(xmask, wg, wout);
    k_z    <<<64,   256, 0, stream>>>(x, xmask, E, zout);
}